// Round 13
// baseline (980.638 us; speedup 1.0000x reference)
//
#include <hip/hip_runtime.h>

// GraphConv: out[t] += input[s] * (esgn*enorm), 3.2M edges, 100K nodes, D=32 fp32.
// Round 24 == Round 23 resubmitted (R12 bench was GPUAcquisitionTimeout infra
// failure; kernel never ran). R22's hipLaunchCooperativeKernel never executed
// (absmax == max|ref| => output zeros => launch API failed under graph capture;
// logic untested, not refuted). Same fused pipeline under a PLAIN launch with
// a hand-rolled generation grid-barrier (device-scope __hip_atomic acq/rel).
// Residency by construction (50.7KB LDS, 1024thr, VGPR<=64 via
// __launch_bounds__(1024,8) -> 2 blocks/CU x 256 CU = 512), verified at
// runtime via hipOccupancyMaxActiveBlocksPerMultiprocessor (host query);
// insufficient -> VERIFIED R18 5-kernel pipeline fallback below. Spin has a
// bounded safety valve (breaks, fails visibly, no hang).
// Phases: hist -> per-bucket scan (nblk-wide subgroups) -> block-0 base scan
// -> deterministic scatter -> persistent bucket accum (all R18-verified logic).

#define NBLK_MAX 512
#define NT   1024
#define KMAX 1024         // max buckets (span 128 -> n_nodes <= 131072)
#define SPAN_SHIFT 7
#define SPAN 128
#define CAP  6144         // accum LDS record capacity (48KB)
#define G    256          // fallback pipeline chunk count
#define NB   256

struct SMem {
    union {
        int lh[KMAX];                          // hist: 4 KB
        int part[NT];                          // scans: 4 KB
        struct { int gbase[KMAX]; int lh2[KMAX]; } sc;   // scatter: 8 KB
        struct {
            int2 srec[CAP];                    // 48 KB
            int lcnt[SPAN], lbeg[SPAN], lcur[SPAN];
        } ac;                                  // 50.7 KB total
    };
};

__device__ __forceinline__ void gridbar(int* bar_cnt, int* bar_gen, int nblk)
{
    __threadfence();
    __syncthreads();
    if (threadIdx.x == 0) {
        int gen = __hip_atomic_load(bar_gen, __ATOMIC_ACQUIRE,
                                    __HIP_MEMORY_SCOPE_AGENT);
        int v = __hip_atomic_fetch_add(bar_cnt, 1, __ATOMIC_ACQ_REL,
                                       __HIP_MEMORY_SCOPE_AGENT);
        if (v == nblk - 1) {
            __hip_atomic_store(bar_cnt, 0, __ATOMIC_RELAXED,
                               __HIP_MEMORY_SCOPE_AGENT);
            __hip_atomic_store(bar_gen, gen + 1, __ATOMIC_RELEASE,
                               __HIP_MEMORY_SCOPE_AGENT);
        } else {
            long spins = 0;
            while (__hip_atomic_load(bar_gen, __ATOMIC_ACQUIRE,
                                     __HIP_MEMORY_SCOPE_AGENT) == gen) {
                __builtin_amdgcn_s_sleep(8);
                if (++spins > (1L << 20)) break;   // ~0.2s safety valve
            }
        }
    }
    __syncthreads();
    __threadfence();
}

__global__ __launch_bounds__(NT, 8) void fused_pipeline(
    const float* __restrict__ input,
    const int* __restrict__ sidx, const int* __restrict__ tidx,
    const float* __restrict__ enorm, const float* __restrict__ esgn,
    int* __restrict__ cnt, int* __restrict__ pref, int* __restrict__ tot,
    int* __restrict__ bbase, int2* __restrict__ recs,
    int* __restrict__ bar_cnt, int* __restrict__ bar_gen,
    float* __restrict__ out,
    int n_edges, int n_nodes, int K, int epb, int vec, int nblk)
{
    __shared__ SMem u;
    int g = blockIdx.x, t = threadIdx.x;

    // ---- P1: per-chunk histogram -> cnt[g][b] ----
    u.lh[t] = 0;
    __syncthreads();
    {
        int beg = g * epb;
        int lim = beg + epb; if (lim > n_edges) lim = n_edges;
        if (vec) {
            int nq = (lim > beg) ? ((lim - beg) >> 2) : 0;
            for (int q = t; q < nq; q += NT) {
                int4 tn = *(const int4*)(tidx + beg + q * 4);
                atomicAdd(&u.lh[tn.x >> SPAN_SHIFT], 1);
                atomicAdd(&u.lh[tn.y >> SPAN_SHIFT], 1);
                atomicAdd(&u.lh[tn.z >> SPAN_SHIFT], 1);
                atomicAdd(&u.lh[tn.w >> SPAN_SHIFT], 1);
            }
            for (int e = beg + (nq << 2) + t; e < lim; e += NT)
                atomicAdd(&u.lh[tidx[e] >> SPAN_SHIFT], 1);
        } else {
            for (int e = beg + t; e < lim; e += NT)
                atomicAdd(&u.lh[tidx[e] >> SPAN_SHIFT], 1);
        }
        __syncthreads();
        cnt[g * KMAX + t] = u.lh[t];
    }
    gridbar(bar_cnt, bar_gen, nblk);

    // ---- P2: per-bucket exclusive scan over chunks (nblk-wide subgroups) ----
    {
        int bpb = KMAX / nblk;         // buckets per block (2 @512, 4 @256)
        int s = t / nblk;              // subgroup id
        int l = t - s * nblk;          // chunk index
        int b = g * bpb + s;           // bucket
        int c = cnt[l * KMAX + b];
        u.part[t] = c;
        __syncthreads();
        for (int off = 1; off < nblk; off <<= 1) {
            int v = (l >= off) ? u.part[t - off] : 0;
            __syncthreads();
            u.part[t] += v;
            __syncthreads();
        }
        pref[l * KMAX + b] = u.part[t] - c;
        if (l == nblk - 1) tot[b] = u.part[t];
    }
    gridbar(bar_cnt, bar_gen, nblk);

    // ---- P3: bucket-base exclusive scan (block 0 only; 1024 entries) ----
    if (g == 0) {
        int c = tot[t];
        u.part[t] = c;
        __syncthreads();
        for (int off = 1; off < KMAX; off <<= 1) {
            int v = (t >= off) ? u.part[t - off] : 0;
            __syncthreads();
            u.part[t] += v;
            __syncthreads();
        }
        bbase[t] = u.part[t] - c;
        if (t == KMAX - 1) bbase[KMAX] = u.part[t];
    }
    gridbar(bar_cnt, bar_gen, nblk);

    // ---- P4: deterministic scatter (chunk g; LDS rank; verified R18) ----
    {
        u.sc.gbase[t] = bbase[t] + pref[g * KMAX + t];
        u.sc.lh2[t] = 0;
        __syncthreads();
        int beg = g * epb;
        int lim = beg + epb; if (lim > n_edges) lim = n_edges;

        #define SCAT_EDGE(tn_, sn_, w_) {                                    \
            int b_ = (tn_) >> SPAN_SHIFT;                                    \
            int rank_ = atomicAdd(&u.sc.lh2[b_], 1);                         \
            unsigned rec_ = ((unsigned)(sn_) << SPAN_SHIFT) |                \
                            (unsigned)((tn_) & (SPAN - 1));                  \
            recs[u.sc.gbase[b_] + rank_] =                                   \
                make_int2((int)rec_, __float_as_int(w_)); }

        if (vec) {
            int nq = (lim > beg) ? ((lim - beg) >> 2) : 0;
            for (int q = t; q < nq; q += NT) {
                int e = beg + q * 4;
                int4   tn = *(const int4*)(tidx + e);
                int4   sn = *(const int4*)(sidx + e);
                float4 nw = *(const float4*)(enorm + e);
                float4 sw = *(const float4*)(esgn + e);
                SCAT_EDGE(tn.x, sn.x, nw.x * sw.x);
                SCAT_EDGE(tn.y, sn.y, nw.y * sw.y);
                SCAT_EDGE(tn.z, sn.z, nw.z * sw.z);
                SCAT_EDGE(tn.w, sn.w, nw.w * sw.w);
            }
            for (int e = beg + (nq << 2) + t; e < lim; e += NT) {
                int tn = tidx[e]; int sn = sidx[e];
                float w = enorm[e] * esgn[e];
                SCAT_EDGE(tn, sn, w);
            }
        } else {
            for (int e = beg + t; e < lim; e += NT) {
                int tn = tidx[e]; int sn = sidx[e];
                float w = enorm[e] * esgn[e];
                SCAT_EDGE(tn, sn, w);
            }
        }
        #undef SCAT_EDGE
    }
    gridbar(bar_cnt, bar_gen, nblk);

    // ---- P5: persistent bucket accum (R18 two-pass body, verified) ----
    for (int b = g; b < K; b += nblk) {
        __syncthreads();            // protect LDS reuse across iterations
        int bstart = bbase[b], bend = bbase[b + 1];
        int base_node = b << SPAN_SHIFT;

        if (bend - bstart <= CAP) {
            if (t < SPAN) u.ac.lcnt[t] = 0;
            __syncthreads();
            for (int i = bstart + t; i < bend; i += NT)
                atomicAdd(&u.ac.lcnt[recs[i].x & (SPAN - 1)], 1);
            __syncthreads();
            int c = (t < SPAN) ? u.ac.lcnt[t] : 0;
            if (t < SPAN) u.ac.lbeg[t] = c;
            __syncthreads();
            for (int off = 1; off < SPAN; off <<= 1) {
                int v = (t < SPAN && t >= off) ? u.ac.lbeg[t - off] : 0;
                __syncthreads();
                if (t < SPAN) u.ac.lbeg[t] += v;
                __syncthreads();
            }
            if (t < SPAN) {
                int excl = u.ac.lbeg[t] - c;
                u.ac.lbeg[t] = excl;
                u.ac.lcur[t] = excl;
            }
            __syncthreads();
            for (int i = bstart + t; i < bend; i += NT) {
                int2 r = recs[i];
                int pos = atomicAdd(&u.ac.lcur[r.x & (SPAN - 1)], 1);
                u.ac.srec[pos] = r;
            }
            __syncthreads();
            int node = t >> 3;
            int lane = t & 7;
            int beg = u.ac.lbeg[node];
            int end = beg + u.ac.lcnt[node];
            float4 acc = make_float4(0.f, 0.f, 0.f, 0.f);
            int i = beg;
            for (; i + 3 < end; i += 4) {
                int2 q0 = u.ac.srec[i];
                int2 q1 = u.ac.srec[i + 1];
                int2 q2 = u.ac.srec[i + 2];
                int2 q3 = u.ac.srec[i + 3];
                float4 v0 = ((const float4*)(input + (size_t)(((unsigned)q0.x) >> SPAN_SHIFT) * 32))[lane];
                float4 v1 = ((const float4*)(input + (size_t)(((unsigned)q1.x) >> SPAN_SHIFT) * 32))[lane];
                float4 v2 = ((const float4*)(input + (size_t)(((unsigned)q2.x) >> SPAN_SHIFT) * 32))[lane];
                float4 v3 = ((const float4*)(input + (size_t)(((unsigned)q3.x) >> SPAN_SHIFT) * 32))[lane];
                float w0 = __int_as_float(q0.y);
                float w1 = __int_as_float(q1.y);
                float w2 = __int_as_float(q2.y);
                float w3 = __int_as_float(q3.y);
                acc.x = fmaf(w0, v0.x, acc.x);
                acc.y = fmaf(w0, v0.y, acc.y);
                acc.z = fmaf(w0, v0.z, acc.z);
                acc.w = fmaf(w0, v0.w, acc.w);
                acc.x = fmaf(w1, v1.x, acc.x);
                acc.y = fmaf(w1, v1.y, acc.y);
                acc.z = fmaf(w1, v1.z, acc.z);
                acc.w = fmaf(w1, v1.w, acc.w);
                acc.x = fmaf(w2, v2.x, acc.x);
                acc.y = fmaf(w2, v2.y, acc.y);
                acc.z = fmaf(w2, v2.z, acc.z);
                acc.w = fmaf(w2, v2.w, acc.w);
                acc.x = fmaf(w3, v3.x, acc.x);
                acc.y = fmaf(w3, v3.y, acc.y);
                acc.z = fmaf(w3, v3.z, acc.z);
                acc.w = fmaf(w3, v3.w, acc.w);
            }
            for (; i < end; ++i) {
                int2 q = u.ac.srec[i];
                float w = __int_as_float(q.y);
                float4 v = ((const float4*)(input + (size_t)(((unsigned)q.x) >> SPAN_SHIFT) * 32))[lane];
                acc.x = fmaf(w, v.x, acc.x);
                acc.y = fmaf(w, v.y, acc.y);
                acc.z = fmaf(w, v.z, acc.z);
                acc.w = fmaf(w, v.w, acc.w);
            }
            int gnode = base_node + node;
            if (gnode < n_nodes)
                ((float4*)(out + (size_t)gnode * 32))[lane] = acc;
        } else {
            // overflow fallback (correctness only; ~never on random data)
            for (int i = t; i < SPAN * 32; i += NT) {
                int gn = base_node + (i >> 5);
                if (gn < n_nodes) out[(size_t)gn * 32 + (i & 31)] = 0.f;
            }
            __syncthreads();
            for (int i = bstart + t; i < bend; i += NT) {
                int2 r = recs[i];
                float w = __int_as_float(r.y);
                int s = (int)(((unsigned)r.x) >> SPAN_SHIFT);
                int gn = base_node + (r.x & (SPAN - 1));
                if (gn < n_nodes)
                    for (int j = 0; j < 32; ++j)
                        atomicAdd(&out[(size_t)gn * 32 + j],
                                  w * input[(size_t)s * 32 + j]);
            }
        }
    }
}

// ======== VERIFIED R18 5-kernel fallback pipeline ========

__global__ __launch_bounds__(1024) void hist_kernel(
    const int* __restrict__ tidx, int* __restrict__ cnt,
    int n_edges, int epb, int vec)
{
    __shared__ int lh[KMAX];
    int g = blockIdx.x, t = threadIdx.x;
    lh[t] = 0;
    __syncthreads();
    int beg = g * epb;
    int lim = beg + epb; if (lim > n_edges) lim = n_edges;
    if (vec) {
        int nq = (lim > beg) ? ((lim - beg) >> 2) : 0;
        for (int q = t; q < nq; q += 1024) {
            int4 tn = *(const int4*)(tidx + beg + q * 4);
            atomicAdd(&lh[tn.x >> SPAN_SHIFT], 1);
            atomicAdd(&lh[tn.y >> SPAN_SHIFT], 1);
            atomicAdd(&lh[tn.z >> SPAN_SHIFT], 1);
            atomicAdd(&lh[tn.w >> SPAN_SHIFT], 1);
        }
        for (int e = beg + (nq << 2) + t; e < lim; e += 1024)
            atomicAdd(&lh[tidx[e] >> SPAN_SHIFT], 1);
    } else {
        for (int e = beg + t; e < lim; e += 1024)
            atomicAdd(&lh[tidx[e] >> SPAN_SHIFT], 1);
    }
    __syncthreads();
    cnt[g * KMAX + t] = lh[t];
}

__global__ __launch_bounds__(G) void scan1_kernel(
    const int* __restrict__ cnt, int* __restrict__ pref, int* __restrict__ tot)
{
    __shared__ int part[G];
    int b = blockIdx.x, t = threadIdx.x;
    int c = cnt[t * KMAX + b];
    part[t] = c;
    __syncthreads();
    for (int off = 1; off < G; off <<= 1) {
        int v = (t >= off) ? part[t - off] : 0;
        __syncthreads();
        part[t] += v;
        __syncthreads();
    }
    pref[t * KMAX + b] = part[t] - c;
    if (t == G - 1) tot[b] = part[t];
}

__global__ __launch_bounds__(KMAX) void bscan_kernel(
    const int* __restrict__ tot, int* __restrict__ bbase)
{
    __shared__ int part[KMAX];
    int t = threadIdx.x;
    int c = tot[t];
    part[t] = c;
    __syncthreads();
    for (int off = 1; off < KMAX; off <<= 1) {
        int v = (t >= off) ? part[t - off] : 0;
        __syncthreads();
        part[t] += v;
        __syncthreads();
    }
    bbase[t] = part[t] - c;
    if (t == KMAX - 1) bbase[KMAX] = part[t];
}

__global__ __launch_bounds__(1024) void scatter_kernel(
    const int* __restrict__ sidx, const int* __restrict__ tidx,
    const float* __restrict__ enorm, const float* __restrict__ esgn,
    const int* __restrict__ bbase, const int* __restrict__ pref,
    int2* __restrict__ recs, int n_edges, int epb, int vec)
{
    __shared__ int gbase[KMAX];
    __shared__ int lh[KMAX];
    int g = blockIdx.x, t = threadIdx.x;
    gbase[t] = bbase[t] + pref[g * KMAX + t];
    lh[t] = 0;
    __syncthreads();
    int beg = g * epb;
    int lim = beg + epb; if (lim > n_edges) lim = n_edges;

    #define SCAT_EDGE(tn_, sn_, w_) {                                        \
        int b_ = (tn_) >> SPAN_SHIFT;                                        \
        int rank_ = atomicAdd(&lh[b_], 1);                                   \
        unsigned rec_ = ((unsigned)(sn_) << SPAN_SHIFT) |                    \
                        (unsigned)((tn_) & (SPAN - 1));                      \
        recs[gbase[b_] + rank_] = make_int2((int)rec_, __float_as_int(w_)); }

    if (vec) {
        int nq = (lim > beg) ? ((lim - beg) >> 2) : 0;
        for (int q = t; q < nq; q += 1024) {
            int e = beg + q * 4;
            int4   tn = *(const int4*)(tidx + e);
            int4   sn = *(const int4*)(sidx + e);
            float4 nw = *(const float4*)(enorm + e);
            float4 sw = *(const float4*)(esgn + e);
            SCAT_EDGE(tn.x, sn.x, nw.x * sw.x);
            SCAT_EDGE(tn.y, sn.y, nw.y * sw.y);
            SCAT_EDGE(tn.z, sn.z, nw.z * sw.z);
            SCAT_EDGE(tn.w, sn.w, nw.w * sw.w);
        }
        for (int e = beg + (nq << 2) + t; e < lim; e += 1024) {
            int tn = tidx[e]; int sn = sidx[e];
            float w = enorm[e] * esgn[e];
            SCAT_EDGE(tn, sn, w);
        }
    } else {
        for (int e = beg + t; e < lim; e += 1024) {
            int tn = tidx[e]; int sn = sidx[e];
            float w = enorm[e] * esgn[e];
            SCAT_EDGE(tn, sn, w);
        }
    }
    #undef SCAT_EDGE
}

__global__ __launch_bounds__(1024) void bucket_accum(
    const float* __restrict__ input, const int2* __restrict__ recs,
    const int* __restrict__ bbase, float* __restrict__ out, int n_nodes)
{
    __shared__ int2 srec[CAP];
    __shared__ int lcnt[SPAN];
    __shared__ int lbeg[SPAN];
    __shared__ int lcur[SPAN];
    int b = blockIdx.x;
    int t = threadIdx.x;
    int bstart = bbase[b], bend = bbase[b + 1];
    int base_node = b << SPAN_SHIFT;

    if (bend - bstart <= CAP) {
        if (t < SPAN) lcnt[t] = 0;
        __syncthreads();
        for (int i = bstart + t; i < bend; i += 1024)
            atomicAdd(&lcnt[recs[i].x & (SPAN - 1)], 1);
        __syncthreads();
        int c = (t < SPAN) ? lcnt[t] : 0;
        if (t < SPAN) lbeg[t] = c;
        __syncthreads();
        for (int off = 1; off < SPAN; off <<= 1) {
            int v = (t < SPAN && t >= off) ? lbeg[t - off] : 0;
            __syncthreads();
            if (t < SPAN) lbeg[t] += v;
            __syncthreads();
        }
        if (t < SPAN) {
            int excl = lbeg[t] - c;
            lbeg[t] = excl;
            lcur[t] = excl;
        }
        __syncthreads();
        for (int i = bstart + t; i < bend; i += 1024) {
            int2 r = recs[i];
            int pos = atomicAdd(&lcur[r.x & (SPAN - 1)], 1);
            srec[pos] = r;
        }
        __syncthreads();
        int node = t >> 3;
        int lane = t & 7;
        int beg = lbeg[node];
        int end = beg + lcnt[node];
        float4 acc = make_float4(0.f, 0.f, 0.f, 0.f);
        int i = beg;
        for (; i + 3 < end; i += 4) {
            int2 q0 = srec[i];
            int2 q1 = srec[i + 1];
            int2 q2 = srec[i + 2];
            int2 q3 = srec[i + 3];
            float4 v0 = ((const float4*)(input + (size_t)(((unsigned)q0.x) >> SPAN_SHIFT) * 32))[lane];
            float4 v1 = ((const float4*)(input + (size_t)(((unsigned)q1.x) >> SPAN_SHIFT) * 32))[lane];
            float4 v2 = ((const float4*)(input + (size_t)(((unsigned)q2.x) >> SPAN_SHIFT) * 32))[lane];
            float4 v3 = ((const float4*)(input + (size_t)(((unsigned)q3.x) >> SPAN_SHIFT) * 32))[lane];
            float w0 = __int_as_float(q0.y);
            float w1 = __int_as_float(q1.y);
            float w2 = __int_as_float(q2.y);
            float w3 = __int_as_float(q3.y);
            acc.x = fmaf(w0, v0.x, acc.x);
            acc.y = fmaf(w0, v0.y, acc.y);
            acc.z = fmaf(w0, v0.z, acc.z);
            acc.w = fmaf(w0, v0.w, acc.w);
            acc.x = fmaf(w1, v1.x, acc.x);
            acc.y = fmaf(w1, v1.y, acc.y);
            acc.z = fmaf(w1, v1.z, acc.z);
            acc.w = fmaf(w1, v1.w, acc.w);
            acc.x = fmaf(w2, v2.x, acc.x);
            acc.y = fmaf(w2, v2.y, acc.y);
            acc.z = fmaf(w2, v2.z, acc.z);
            acc.w = fmaf(w2, v2.w, acc.w);
            acc.x = fmaf(w3, v3.x, acc.x);
            acc.y = fmaf(w3, v3.y, acc.y);
            acc.z = fmaf(w3, v3.z, acc.z);
            acc.w = fmaf(w3, v3.w, acc.w);
        }
        for (; i < end; ++i) {
            int2 q = srec[i];
            float w = __int_as_float(q.y);
            float4 v = ((const float4*)(input + (size_t)(((unsigned)q.x) >> SPAN_SHIFT) * 32))[lane];
            acc.x = fmaf(w, v.x, acc.x);
            acc.y = fmaf(w, v.y, acc.y);
            acc.z = fmaf(w, v.z, acc.z);
            acc.w = fmaf(w, v.w, acc.w);
        }
        int gnode = base_node + node;
        if (gnode < n_nodes)
            ((float4*)(out + (size_t)gnode * 32))[lane] = acc;
    } else {
        for (int i = t; i < SPAN * 32; i += 1024) {
            int gn = base_node + (i >> 5);
            if (gn < n_nodes) out[(size_t)gn * 32 + (i & 31)] = 0.f;
        }
        __syncthreads();
        for (int i = bstart + t; i < bend; i += 1024) {
            int2 r = recs[i];
            float w = __int_as_float(r.y);
            int s = (int)(((unsigned)r.x) >> SPAN_SHIFT);
            int gn = base_node + (r.x & (SPAN - 1));
            if (gn < n_nodes)
                for (int j = 0; j < 32; ++j)
                    atomicAdd(&out[(size_t)gn * 32 + j], w * input[(size_t)s * 32 + j]);
        }
    }
}

// Last-resort fallback (R3): direct atomic scatter.
__global__ __launch_bounds__(NB) void graphconv_scatter(
    const float* __restrict__ input, const int* __restrict__ sidx,
    const int* __restrict__ tidx, const float* __restrict__ enorm,
    const float* __restrict__ esgn, float* __restrict__ out, int n_edges)
{
    int t = blockIdx.x * NB + threadIdx.x;
    int e = t >> 3;
    int sub = t & 7;
    if (e >= n_edges) return;
    int s = sidx[e];
    int d = tidx[e];
    float w = enorm[e] * esgn[e];
    const float4* src = (const float4*)(input + (size_t)s * 32);
    float4 v = src[sub];
    float* op = out + (size_t)d * 32 + sub * 4;
    atomicAdd(op + 0, v.x * w);
    atomicAdd(op + 1, v.y * w);
    atomicAdd(op + 2, v.z * w);
    atomicAdd(op + 3, v.w * w);
}

extern "C" void kernel_launch(void* const* d_in, const int* in_sizes, int n_in,
                              void* d_out, int out_size, void* d_ws, size_t ws_size,
                              hipStream_t stream) {
    const float* input = (const float*)d_in[0];
    const int*   eidx  = (const int*)d_in[1];   // int64 in reference -> int32 here
    const float* enorm = (const float*)d_in[2];
    const float* esgn  = (const float*)d_in[3];
    float*       out   = (float*)d_out;

    int n_edges = in_sizes[1] / 2;             // eidx is (2, n_edges)
    int n_nodes = in_sizes[0] / 32;            // input is (n_nodes, 32)
    const int* sidx = (const int*)eidx;
    const int* tidx = (const int*)eidx + n_edges;

    int K = (n_nodes + SPAN - 1) >> SPAN_SHIFT;   // 782 for 100K nodes

    // Workspace: recs[E int2] | cnt[NBLK_MAX*KMAX] | pref[NBLK_MAX*KMAX]
    //            | tot[KMAX] | bbase[KMAX+1] | bar_cnt | bar_gen
    size_t need = (size_t)n_edges * 8 +
                  ((size_t)2 * NBLK_MAX * KMAX + 2 * KMAX + 1 + 2) * 4;

    if (ws_size >= need && K <= KMAX) {
        int2* recs    = (int2*)d_ws;
        int*  cnt     = (int*)(recs + n_edges);
        int*  pref    = cnt + (size_t)NBLK_MAX * KMAX;
        int*  tot     = pref + (size_t)NBLK_MAX * KMAX;
        int*  bbase   = tot + KMAX;
        int*  bar_cnt = bbase + (KMAX + 1);
        int*  bar_gen = bar_cnt + 1;

        int vec = ((n_edges & 3) == 0 &&
                   (((uintptr_t)tidx | (uintptr_t)sidx |
                     (uintptr_t)enorm | (uintptr_t)esgn) & 15) == 0) ? 1 : 0;

        // Can the fused persistent grid be fully co-resident?
        int maxb = 0;
        hipError_t qe = hipOccupancyMaxActiveBlocksPerMultiprocessor(
            &maxb, (const void*)fused_pipeline, NT, 0);
        int nblk = 0;
        if (qe == hipSuccess && maxb >= 1) {
            nblk = (maxb >= 2) ? 512 : 256;   // both divide KMAX
        }

        if (nblk > 0) {
            int epb = ((n_edges + nblk - 1) / nblk + 3) & ~3;
            hipMemsetAsync(bar_cnt, 0, 2 * sizeof(int), stream);
            fused_pipeline<<<nblk, NT, 0, stream>>>(
                input, sidx, tidx, enorm, esgn,
                cnt, pref, tot, bbase, recs, bar_cnt, bar_gen, out,
                n_edges, n_nodes, K, epb, vec, nblk);
        } else {
            int epb = ((n_edges + G - 1) / G + 3) & ~3;
            hist_kernel   <<<G,    1024, 0, stream>>>(tidx, cnt, n_edges, epb, vec);
            scan1_kernel  <<<KMAX, G,    0, stream>>>(cnt, pref, tot);
            bscan_kernel  <<<1,    KMAX, 0, stream>>>(tot, bbase);
            scatter_kernel<<<G,    1024, 0, stream>>>(sidx, tidx, enorm, esgn,
                                                      bbase, pref, recs,
                                                      n_edges, epb, vec);
            bucket_accum  <<<K,    1024, 0, stream>>>(input, recs, bbase,
                                                      out, n_nodes);
        }
    } else {
        hipMemsetAsync(d_out, 0, (size_t)out_size * sizeof(float), stream);
        size_t threads_total = (size_t)n_edges * 8;
        int grid = (int)((threads_total + NB - 1) / NB);
        graphconv_scatter<<<grid, NB, 0, stream>>>(input, sidx, tidx, enorm, esgn,
                                                   out, n_edges);
    }
}

// Round 15
// 198.249 us; speedup vs baseline: 4.9465x; 4.9465x over previous
//
#include <hip/hip_runtime.h>

// GraphConv: out[t] += input[s] * (esgn*enorm), 3.2M edges, 100K nodes, D=32 fp32.
// Round 26 == Round 25 resubmitted (R14 bench was GPUAcquisitionTimeout infra
// failure; kernel never ran). R24's grid-barrier fusion REFUTED on hardware
// (1592us, occ 98%, VALU 0.6%: device-scope fences force per-barrier L2
// writeback/invalidate on the 8 non-coherent XCDs -- FETCH 195MB/WRITE 124MB,
// cross-phase caching destroyed). The ~13us inter-kernel gap IS the hardware's
// coherence drain; multi-phase algorithms stay multi-kernel on this arch.
// This is the verified R18 pipeline with one safe fold: bscan launch deleted --
// scatter and bucket_accum each recompute the 1024-entry bucket-base scan
// locally from tot (4KB, L2-hot, ~1us LDS scan per block).
// Pipeline (4 kernels): hist -> scan1 -> scatter(+local bscan) -> accum(+local bscan).

#define G    256          // edge chunks / scatter blocks
#define KMAX 1024         // max buckets (span 128 -> n_nodes <= 131072)
#define SPAN_SHIFT 7
#define SPAN 128
#define CAP  6144         // bucket_accum LDS record capacity (48KB)
#define NB   256

// Per-chunk histogram: cnt[g*KMAX + b]. Coalesced matrix write, no atomics
// beyond LDS. (Verified R18.)
__global__ __launch_bounds__(1024) void hist_kernel(
    const int* __restrict__ tidx, int* __restrict__ cnt,
    int n_edges, int epb, int vec)
{
    __shared__ int lh[KMAX];
    int g = blockIdx.x, t = threadIdx.x;
    lh[t] = 0;
    __syncthreads();
    int beg = g * epb;
    int lim = beg + epb; if (lim > n_edges) lim = n_edges;
    if (vec) {
        int nq = (lim > beg) ? ((lim - beg) >> 2) : 0;
        for (int q = t; q < nq; q += 1024) {
            int4 tn = *(const int4*)(tidx + beg + q * 4);
            atomicAdd(&lh[tn.x >> SPAN_SHIFT], 1);
            atomicAdd(&lh[tn.y >> SPAN_SHIFT], 1);
            atomicAdd(&lh[tn.z >> SPAN_SHIFT], 1);
            atomicAdd(&lh[tn.w >> SPAN_SHIFT], 1);
        }
        for (int e = beg + (nq << 2) + t; e < lim; e += 1024)
            atomicAdd(&lh[tidx[e] >> SPAN_SHIFT], 1);
    } else {
        for (int e = beg + t; e < lim; e += 1024)
            atomicAdd(&lh[tidx[e] >> SPAN_SHIFT], 1);
    }
    __syncthreads();
    cnt[g * KMAX + t] = lh[t];
}

// Per-bucket exclusive scan over the G chunk counts -> pref[g][b], tot[b].
// (Verified R18.)
__global__ __launch_bounds__(G) void scan1_kernel(
    const int* __restrict__ cnt, int* __restrict__ pref, int* __restrict__ tot)
{
    __shared__ int part[G];
    int b = blockIdx.x, t = threadIdx.x;
    int c = cnt[t * KMAX + b];
    part[t] = c;
    __syncthreads();
    for (int off = 1; off < G; off <<= 1) {
        int v = (t >= off) ? part[t - off] : 0;
        __syncthreads();
        part[t] += v;
        __syncthreads();
    }
    pref[t * KMAX + b] = part[t] - c;
    if (t == G - 1) tot[b] = part[t];
}

// Deterministic scatter: block g owns chunk g; position = gbase[b] + LDS rank.
// R25: bucket-base scan computed locally from tot (bscan kernel deleted).
__global__ __launch_bounds__(1024) void scatter_kernel(
    const int* __restrict__ sidx, const int* __restrict__ tidx,
    const float* __restrict__ enorm, const float* __restrict__ esgn,
    const int* __restrict__ tot, const int* __restrict__ pref,
    int2* __restrict__ recs, int n_edges, int epb, int vec)
{
    __shared__ int gbase[KMAX];
    __shared__ int lh[KMAX];
    __shared__ int part[KMAX];
    int g = blockIdx.x, t = threadIdx.x;

    // local exclusive scan of tot -> bucket bases
    int c = tot[t];
    part[t] = c;
    __syncthreads();
    for (int off = 1; off < KMAX; off <<= 1) {
        int v = (t >= off) ? part[t - off] : 0;
        __syncthreads();
        part[t] += v;
        __syncthreads();
    }
    gbase[t] = (part[t] - c) + pref[g * KMAX + t];
    lh[t] = 0;
    __syncthreads();

    int beg = g * epb;
    int lim = beg + epb; if (lim > n_edges) lim = n_edges;

    #define SCAT_EDGE(tn_, sn_, w_) {                                        \
        int b_ = (tn_) >> SPAN_SHIFT;                                        \
        int rank_ = atomicAdd(&lh[b_], 1);                                   \
        unsigned rec_ = ((unsigned)(sn_) << SPAN_SHIFT) |                    \
                        (unsigned)((tn_) & (SPAN - 1));                      \
        recs[gbase[b_] + rank_] = make_int2((int)rec_, __float_as_int(w_)); }

    if (vec) {
        int nq = (lim > beg) ? ((lim - beg) >> 2) : 0;
        for (int q = t; q < nq; q += 1024) {
            int e = beg + q * 4;
            int4   tn = *(const int4*)(tidx + e);
            int4   sn = *(const int4*)(sidx + e);
            float4 nw = *(const float4*)(enorm + e);
            float4 sw = *(const float4*)(esgn + e);
            SCAT_EDGE(tn.x, sn.x, nw.x * sw.x);
            SCAT_EDGE(tn.y, sn.y, nw.y * sw.y);
            SCAT_EDGE(tn.z, sn.z, nw.z * sw.z);
            SCAT_EDGE(tn.w, sn.w, nw.w * sw.w);
        }
        for (int e = beg + (nq << 2) + t; e < lim; e += 1024) {
            int tn = tidx[e]; int sn = sidx[e];
            float w = enorm[e] * esgn[e];
            SCAT_EDGE(tn, sn, w);
        }
    } else {
        for (int e = beg + t; e < lim; e += 1024) {
            int tn = tidx[e]; int sn = sidx[e];
            float w = enorm[e] * esgn[e];
            SCAT_EDGE(tn, sn, w);
        }
    }
    #undef SCAT_EDGE
}

// Fused node-sort + accumulate, one block per bucket (128 nodes).
// R25: bucket range [bstart,bend) derived from a local scan of tot
// (bscan kernel deleted); body otherwise the verified R18 two-pass form.
__global__ __launch_bounds__(1024) void bucket_accum(
    const float* __restrict__ input, const int2* __restrict__ recs,
    const int* __restrict__ tot, float* __restrict__ out, int n_nodes)
{
    __shared__ int2 srec[CAP];             // 48 KB
    __shared__ int part[KMAX];             // 4 KB (scan prologue)
    __shared__ int lcnt[SPAN];
    __shared__ int lbeg[SPAN];
    __shared__ int lcur[SPAN];
    __shared__ int sb[2];
    int b = blockIdx.x;
    int t = threadIdx.x;

    // local exclusive scan of tot -> this bucket's [bstart, bend)
    int c = tot[t];
    part[t] = c;
    __syncthreads();
    for (int off = 1; off < KMAX; off <<= 1) {
        int v = (t >= off) ? part[t - off] : 0;
        __syncthreads();
        part[t] += v;
        __syncthreads();
    }
    if (t == b) { sb[0] = part[t] - c; sb[1] = part[t]; }
    __syncthreads();
    int bstart = sb[0], bend = sb[1];
    int base_node = b << SPAN_SHIFT;

    if (bend - bstart <= CAP) {
        if (t < SPAN) lcnt[t] = 0;
        __syncthreads();
        for (int i = bstart + t; i < bend; i += 1024)
            atomicAdd(&lcnt[recs[i].x & (SPAN - 1)], 1);
        __syncthreads();
        int cc = (t < SPAN) ? lcnt[t] : 0;
        if (t < SPAN) lbeg[t] = cc;
        __syncthreads();
        for (int off = 1; off < SPAN; off <<= 1) {
            int v = (t < SPAN && t >= off) ? lbeg[t - off] : 0;
            __syncthreads();
            if (t < SPAN) lbeg[t] += v;
            __syncthreads();
        }
        if (t < SPAN) {
            int excl = lbeg[t] - cc;
            lbeg[t] = excl;
            lcur[t] = excl;
        }
        __syncthreads();
        for (int i = bstart + t; i < bend; i += 1024) {
            int2 r = recs[i];
            int pos = atomicAdd(&lcur[r.x & (SPAN - 1)], 1);
            srec[pos] = r;
        }
        __syncthreads();
        int node = t >> 3;
        int lane = t & 7;
        int beg = lbeg[node];
        int end = beg + lcnt[node];
        float4 acc = make_float4(0.f, 0.f, 0.f, 0.f);
        int i = beg;
        for (; i + 3 < end; i += 4) {
            int2 q0 = srec[i];
            int2 q1 = srec[i + 1];
            int2 q2 = srec[i + 2];
            int2 q3 = srec[i + 3];
            float4 v0 = ((const float4*)(input + (size_t)(((unsigned)q0.x) >> SPAN_SHIFT) * 32))[lane];
            float4 v1 = ((const float4*)(input + (size_t)(((unsigned)q1.x) >> SPAN_SHIFT) * 32))[lane];
            float4 v2 = ((const float4*)(input + (size_t)(((unsigned)q2.x) >> SPAN_SHIFT) * 32))[lane];
            float4 v3 = ((const float4*)(input + (size_t)(((unsigned)q3.x) >> SPAN_SHIFT) * 32))[lane];
            float w0 = __int_as_float(q0.y);
            float w1 = __int_as_float(q1.y);
            float w2 = __int_as_float(q2.y);
            float w3 = __int_as_float(q3.y);
            acc.x = fmaf(w0, v0.x, acc.x);
            acc.y = fmaf(w0, v0.y, acc.y);
            acc.z = fmaf(w0, v0.z, acc.z);
            acc.w = fmaf(w0, v0.w, acc.w);
            acc.x = fmaf(w1, v1.x, acc.x);
            acc.y = fmaf(w1, v1.y, acc.y);
            acc.z = fmaf(w1, v1.z, acc.z);
            acc.w = fmaf(w1, v1.w, acc.w);
            acc.x = fmaf(w2, v2.x, acc.x);
            acc.y = fmaf(w2, v2.y, acc.y);
            acc.z = fmaf(w2, v2.z, acc.z);
            acc.w = fmaf(w2, v2.w, acc.w);
            acc.x = fmaf(w3, v3.x, acc.x);
            acc.y = fmaf(w3, v3.y, acc.y);
            acc.z = fmaf(w3, v3.z, acc.z);
            acc.w = fmaf(w3, v3.w, acc.w);
        }
        for (; i < end; ++i) {
            int2 q = srec[i];
            float w = __int_as_float(q.y);
            float4 v = ((const float4*)(input + (size_t)(((unsigned)q.x) >> SPAN_SHIFT) * 32))[lane];
            acc.x = fmaf(w, v.x, acc.x);
            acc.y = fmaf(w, v.y, acc.y);
            acc.z = fmaf(w, v.z, acc.z);
            acc.w = fmaf(w, v.w, acc.w);
        }
        int gnode = base_node + node;
        if (gnode < n_nodes)
            ((float4*)(out + (size_t)gnode * 32))[lane] = acc;
    } else {
        // overflow fallback (correctness only; ~never taken on random data)
        for (int i = t; i < SPAN * 32; i += 1024) {
            int gn = base_node + (i >> 5);
            if (gn < n_nodes) out[(size_t)gn * 32 + (i & 31)] = 0.f;
        }
        __syncthreads();
        for (int i = bstart + t; i < bend; i += 1024) {
            int2 r = recs[i];
            float w = __int_as_float(r.y);
            int s = (int)(((unsigned)r.x) >> SPAN_SHIFT);
            int gn = base_node + (r.x & (SPAN - 1));
            if (gn < n_nodes)
                for (int j = 0; j < 32; ++j)
                    atomicAdd(&out[(size_t)gn * 32 + j], w * input[(size_t)s * 32 + j]);
        }
    }
}

// Last-resort fallback (R3): direct atomic scatter.
__global__ __launch_bounds__(NB) void graphconv_scatter(
    const float* __restrict__ input, const int* __restrict__ sidx,
    const int* __restrict__ tidx, const float* __restrict__ enorm,
    const float* __restrict__ esgn, float* __restrict__ out, int n_edges)
{
    int t = blockIdx.x * NB + threadIdx.x;
    int e = t >> 3;
    int sub = t & 7;
    if (e >= n_edges) return;
    int s = sidx[e];
    int d = tidx[e];
    float w = enorm[e] * esgn[e];
    const float4* src = (const float4*)(input + (size_t)s * 32);
    float4 v = src[sub];
    float* op = out + (size_t)d * 32 + sub * 4;
    atomicAdd(op + 0, v.x * w);
    atomicAdd(op + 1, v.y * w);
    atomicAdd(op + 2, v.z * w);
    atomicAdd(op + 3, v.w * w);
}

extern "C" void kernel_launch(void* const* d_in, const int* in_sizes, int n_in,
                              void* d_out, int out_size, void* d_ws, size_t ws_size,
                              hipStream_t stream) {
    const float* input = (const float*)d_in[0];
    const int*   eidx  = (const int*)d_in[1];   // int64 in reference -> int32 here
    const float* enorm = (const float*)d_in[2];
    const float* esgn  = (const float*)d_in[3];
    float*       out   = (float*)d_out;

    int n_edges = in_sizes[1] / 2;             // eidx is (2, n_edges)
    int n_nodes = in_sizes[0] / 32;            // input is (n_nodes, 32)
    const int* sidx = eidx;
    const int* tidx = eidx + n_edges;

    int K = (n_nodes + SPAN - 1) >> SPAN_SHIFT;   // 782 for 100K nodes

    // Workspace: recs[E int2] | cnt[G*KMAX] | pref[G*KMAX] | tot[KMAX]
    size_t need = (size_t)n_edges * 8 +
                  ((size_t)2 * G * KMAX + KMAX) * 4;

    if (ws_size >= need && K <= KMAX) {
        int2* recs  = (int2*)d_ws;
        int*  cnt   = (int*)(recs + n_edges);
        int*  pref  = cnt + (size_t)G * KMAX;
        int*  tot   = pref + (size_t)G * KMAX;

        // chunk size: multiple of 4 so vector loads stay 16B-aligned
        int epb = ((n_edges + G - 1) / G + 3) & ~3;
        int vec = ((n_edges & 3) == 0 &&
                   (((uintptr_t)tidx | (uintptr_t)sidx |
                     (uintptr_t)enorm | (uintptr_t)esgn) & 15) == 0) ? 1 : 0;

        hist_kernel   <<<G,    1024, 0, stream>>>(tidx, cnt, n_edges, epb, vec);
        scan1_kernel  <<<KMAX, G,    0, stream>>>(cnt, pref, tot);
        scatter_kernel<<<G,    1024, 0, stream>>>(sidx, tidx, enorm, esgn,
                                                  tot, pref, recs,
                                                  n_edges, epb, vec);
        bucket_accum  <<<K,    1024, 0, stream>>>(input, recs, tot,
                                                  out, n_nodes);
    } else {
        hipMemsetAsync(d_out, 0, (size_t)out_size * sizeof(float), stream);
        size_t threads_total = (size_t)n_edges * 8;
        int grid = (int)((threads_total + NB - 1) / NB);
        graphconv_scatter<<<grid, NB, 0, stream>>>(input, sidx, tidx, enorm, esgn,
                                                   out, n_edges);
    }
}